// Round 3
// baseline (682.472 us; speedup 1.0000x reference)
//
#include <hip/hip_runtime.h>
#include <hip/hip_bf16.h>
#include <math.h>

#define NB 128
#define NT 20
#define NS 19
#define NR 49
#define NV 10000
#define NE 512
#define NH 512
#define NFD 512
#define NA 256
#define NG 2048
#define NKC 1536

typedef __bf16 bf16_t;
typedef bf16_t bf16x8 __attribute__((ext_vector_type(8)));
typedef float f32x4 __attribute__((ext_vector_type(4)));

__device__ __forceinline__ float sigm(float x) { return 1.f / (1.f + expf(-x)); }

// ------------------------------------------------------------------
// setup: Wcatb reordered (row n' = 4h+gate), bias reordered, bf16 copies
// of fc_W / W_f / W_h / features, hx=cx=0
// ------------------------------------------------------------------
__global__ __launch_bounds__(256) void k_setup(
    const float* __restrict__ W_ih, const float* __restrict__ W_hh,
    const float* __restrict__ b_ih, const float* __restrict__ b_hh,
    const float* __restrict__ W_h, const float* __restrict__ fc_W,
    const float* __restrict__ W_f, const float* __restrict__ features,
    bf16_t* __restrict__ Wcatb, bf16_t* __restrict__ fcWb,
    bf16_t* __restrict__ Wfb, bf16_t* __restrict__ featb,
    bf16_t* __restrict__ W_hb, float* __restrict__ bias,
    float* __restrict__ hx, float* __restrict__ cx)
{
    int idx = blockIdx.x * 256 + threadIdx.x;
    if (idx < NV * NH) fcWb[idx] = (bf16_t)fc_W[idx];
    if (idx < NG * NKC) {
        int n = idx / NKC, k = idx % NKC;      // n' = 4h + g
        int h = n >> 2, g = n & 3;
        int orig = g * NH + h;
        Wcatb[idx] = (bf16_t)((k < NE + NFD) ? W_ih[orig * (NE + NFD) + k]
                                             : W_hh[orig * NH + (k - NE - NFD)]);
    }
    if (idx < NB * NR * NFD) featb[idx] = (bf16_t)features[idx];
    if (idx < NA * NFD) Wfb[idx] = (bf16_t)W_f[idx];
    if (idx < NA * NH) W_hb[idx] = (bf16_t)W_h[idx];
    if (idx < NG) {
        int h = idx >> 2, g = idx & 3;
        int orig = g * NH + h;
        bias[idx] = b_ih[orig] + b_hh[orig];
    }
    if (idx < NB * NH) { hx[idx] = 0.f; cx[idx] = 0.f; }
}

// ------------------------------------------------------------------
// attention (fp32 math): per-block batch b; writes bf16 lin row
// ------------------------------------------------------------------
__global__ __launch_bounds__(1024) void k_attn(
    const float* __restrict__ hx, const bf16_t* __restrict__ W_hb,
    const float* __restrict__ b_h, const float* __restrict__ fproj,
    const float* __restrict__ v_w, const bf16_t* __restrict__ featb,
    const float* __restrict__ emb, const int* __restrict__ captions,
    bf16_t* __restrict__ lin, int t)
{
    int b = blockIdx.x;
    int tid = threadIdx.x;
    __shared__ float hxs[NH];
    __shared__ float part[4][NA];
    __shared__ float hatt[NA];
    __shared__ float salpha[64];

    if (tid < NH) hxs[tid] = hx[b * NH + tid];
    __syncthreads();

    {   // h = hx @ W_h^T : thread (q,a) does quarter-K dot, W_h rows bf16
        int a = tid & (NA - 1), q = tid >> 8;
        const bf16x8* wrow = (const bf16x8*)(W_hb + (size_t)a * NH + q * 128);
        const float* hq = hxs + q * 128;
        float p = 0.f;
        #pragma unroll
        for (int c = 0; c < 16; ++c) {
            bf16x8 wv = wrow[c];
            int k = c * 8;
            p += hq[k+0]*(float)wv[0] + hq[k+1]*(float)wv[1]
               + hq[k+2]*(float)wv[2] + hq[k+3]*(float)wv[3]
               + hq[k+4]*(float)wv[4] + hq[k+5]*(float)wv[5]
               + hq[k+6]*(float)wv[6] + hq[k+7]*(float)wv[7];
        }
        part[q][a] = p;
    }
    __syncthreads();
    if (tid < NA)
        hatt[tid] = part[0][tid] + part[1][tid] + part[2][tid] + part[3][tid] + b_h[tid];
    __syncthreads();

    {   // scores, 16 waves strided over r
        int wv = tid >> 6, lane = tid & 63;
        for (int r = wv; r < NR; r += 16) {
            float s = 0.f;
            const float* fp = fproj + (size_t)(b * NR + r) * NA;
            #pragma unroll
            for (int j = 0; j < 4; ++j) {
                int aa = lane + 64 * j;
                s += tanhf(hatt[aa] + fp[aa]) * v_w[aa];
            }
            #pragma unroll
            for (int off = 32; off; off >>= 1) s += __shfl_xor(s, off);
            if (lane == 0) salpha[r] = s;
        }
    }
    __syncthreads();

    if (tid < 64) {   // softmax over R=49 in wave 0
        float v = (tid < NR) ? salpha[tid] : -INFINITY;
        float m = v;
        #pragma unroll
        for (int off = 32; off; off >>= 1) m = fmaxf(m, __shfl_xor(m, off));
        float e = (tid < NR) ? expf(v - m) : 0.f;
        float ssum = e;
        #pragma unroll
        for (int off = 32; off; off >>= 1) ssum += __shfl_xor(ssum, off);
        if (tid < NR) salpha[tid] = e / ssum;
    }
    __syncthreads();

    if (tid < NH) {   // context (bf16 features) + concat lstm input row
        bf16_t* lrow = lin + (size_t)b * NKC;
        lrow[tid] = (bf16_t)emb[(size_t)captions[b * NT + t] * NE + tid];
        lrow[NE + NFD + tid] = (bf16_t)hxs[tid];
        float c = 0.f;
        #pragma unroll 7
        for (int r = 0; r < NR; ++r)
            c += salpha[r] * (float)featb[(size_t)(b * NR + r) * NFD + tid];
        lrow[NE + tid] = (bf16_t)c;
    }
}

// ------------------------------------------------------------------
// generic bf16 MFMA GEMM-NT (used for f_proj):
// C[M,N] = A[M,K] @ B[N,K]^T + bias, fp32 out. tile 64x64, BK=64.
// ------------------------------------------------------------------
__global__ __launch_bounds__(256) void gemm_bf16_nt(
    const bf16_t* __restrict__ Am, const bf16_t* __restrict__ Bm,
    const float* __restrict__ bias, float* __restrict__ Cm,
    int M, int N, int K, int ldc)
{
    __shared__ uint4 AsU[512];
    __shared__ uint4 BsU[512];
    int tid = threadIdx.x;
    int m0 = blockIdx.x * 64, n0 = blockIdx.y * 64;
    int nk = K >> 6;

    int rowS = tid >> 3, slotS = tid & 7;
    int wr0 = rowS * 8 + (slotS ^ (rowS & 7));
    int rowS2 = rowS + 32;
    int wr1 = rowS2 * 8 + (slotS ^ (rowS2 & 7));

    const uint4* pA = (const uint4*)(Am + (size_t)(m0 + rowS) * K) + slotS;
    size_t aStep = (size_t)4 * K;
    int nrow0 = n0 + rowS, nrow1 = n0 + rowS2;
    bool bv0 = nrow0 < N, bv1 = nrow1 < N;
    const uint4* pB0 = (const uint4*)(Bm + (size_t)nrow0 * K) + slotS;
    const uint4* pB1 = (const uint4*)(Bm + (size_t)nrow1 * K) + slotS;
    uint4 zz = make_uint4(0, 0, 0, 0);

    int w = tid >> 6, lane = tid & 63;
    int wm = w >> 1, wn = w & 1;
    int lr = lane & 15, lg = lane >> 4;
    int ra[2][2], rb[2][2];
    #pragma unroll
    for (int i = 0; i < 2; ++i)
        #pragma unroll
        for (int kk = 0; kk < 2; ++kk) {
            int rA = wm * 32 + i * 16 + lr;
            int rB = wn * 32 + i * 16 + lr;
            int s = kk * 4 + lg;
            ra[i][kk] = rA * 8 + (s ^ (rA & 7));
            rb[i][kk] = rB * 8 + (s ^ (rB & 7));
        }

    f32x4 acc00 = {}, acc01 = {}, acc10 = {}, acc11 = {};
    uint4 a0 = pA[0], a1 = pA[aStep];
    uint4 b0 = bv0 ? pB0[0] : zz;
    uint4 b1 = bv1 ? pB1[0] : zz;
    pA += 8; pB0 += 8; pB1 += 8;

    for (int kt = 0; kt < nk; ++kt) {
        __syncthreads();
        AsU[wr0] = a0; AsU[wr1] = a1;
        BsU[wr0] = b0; BsU[wr1] = b1;
        if (kt + 1 < nk) {
            a0 = pA[0]; a1 = pA[aStep];
            b0 = bv0 ? pB0[0] : zz;
            b1 = bv1 ? pB1[0] : zz;
            pA += 8; pB0 += 8; pB1 += 8;
        }
        __syncthreads();
        const bf16x8* Af = (const bf16x8*)AsU;
        const bf16x8* Bf = (const bf16x8*)BsU;
        #pragma unroll
        for (int kk = 0; kk < 2; ++kk) {
            bf16x8 fa0 = Af[ra[0][kk]], fa1 = Af[ra[1][kk]];
            bf16x8 fb0 = Bf[rb[0][kk]], fb1 = Bf[rb[1][kk]];
            acc00 = __builtin_amdgcn_mfma_f32_16x16x32_bf16(fa0, fb0, acc00, 0, 0, 0);
            acc01 = __builtin_amdgcn_mfma_f32_16x16x32_bf16(fa0, fb1, acc01, 0, 0, 0);
            acc10 = __builtin_amdgcn_mfma_f32_16x16x32_bf16(fa1, fb0, acc10, 0, 0, 0);
            acc11 = __builtin_amdgcn_mfma_f32_16x16x32_bf16(fa1, fb1, acc11, 0, 0, 0);
        }
    }

    f32x4 av[2][2] = {{acc00, acc01}, {acc10, acc11}};
    #pragma unroll
    for (int i = 0; i < 2; ++i) {
        int mbase = m0 + wm * 32 + i * 16 + lg * 4;
        #pragma unroll
        for (int j = 0; j < 2; ++j) {
            int n = n0 + wn * 32 + j * 16 + lr;
            if (n < N) {
                float bz = bias ? bias[n] : 0.f;
                #pragma unroll
                for (int r = 0; r < 4; ++r)
                    Cm[(size_t)(mbase + r) * ldc + n] = av[i][j][r] + bz;
            }
        }
    }
}

// ------------------------------------------------------------------
// fused step: gates GEMM (128x2048x1536, Wcat rows reordered n'=4h+g)
// + LSTM pointwise epilogue. grid (2,32). Writes hx, cx, hxAll[t].
// ------------------------------------------------------------------
__global__ __launch_bounds__(256) void k_step(
    const bf16_t* __restrict__ lin, const bf16_t* __restrict__ Wcatb,
    const float* __restrict__ bias, float* __restrict__ hx,
    float* __restrict__ cx, bf16_t* __restrict__ hxAll, int t)
{
    __shared__ __align__(16) char smem[16640];
    uint4* AsU = (uint4*)smem;
    uint4* BsU = AsU + 512;

    int tid = threadIdx.x;
    int m0 = blockIdx.x * 64, n0 = blockIdx.y * 64;

    int rowS = tid >> 3, slotS = tid & 7;
    int wr0 = rowS * 8 + (slotS ^ (rowS & 7));
    int rowS2 = rowS + 32;
    int wr1 = rowS2 * 8 + (slotS ^ (rowS2 & 7));

    const uint4* pA = (const uint4*)(lin + (size_t)(m0 + rowS) * NKC) + slotS;
    const uint4* pB0 = (const uint4*)(Wcatb + (size_t)(n0 + rowS) * NKC) + slotS;
    const uint4* pB1 = (const uint4*)(Wcatb + (size_t)(n0 + rowS2) * NKC) + slotS;
    size_t aStep = (size_t)4 * NKC;

    int w = tid >> 6, lane = tid & 63;
    int wm = w >> 1, wn = w & 1;
    int lr = lane & 15, lg = lane >> 4;
    int ra[2][2], rb[2][2];
    #pragma unroll
    for (int i = 0; i < 2; ++i)
        #pragma unroll
        for (int kk = 0; kk < 2; ++kk) {
            int rA = wm * 32 + i * 16 + lr;
            int rB = wn * 32 + i * 16 + lr;
            int s = kk * 4 + lg;
            ra[i][kk] = rA * 8 + (s ^ (rA & 7));
            rb[i][kk] = rB * 8 + (s ^ (rB & 7));
        }

    f32x4 acc00 = {}, acc01 = {}, acc10 = {}, acc11 = {};
    uint4 a0 = pA[0], a1 = pA[aStep];
    uint4 b0 = pB0[0], b1 = pB1[0];
    pA += 8; pB0 += 8; pB1 += 8;

    #pragma unroll 1
    for (int kt = 0; kt < NKC / 64; ++kt) {
        __syncthreads();
        AsU[wr0] = a0; AsU[wr1] = a1;
        BsU[wr0] = b0; BsU[wr1] = b1;
        if (kt + 1 < NKC / 64) {
            a0 = pA[0]; a1 = pA[aStep];
            b0 = pB0[0]; b1 = pB1[0];
            pA += 8; pB0 += 8; pB1 += 8;
        }
        __syncthreads();
        const bf16x8* Af = (const bf16x8*)AsU;
        const bf16x8* Bf = (const bf16x8*)BsU;
        #pragma unroll
        for (int kk = 0; kk < 2; ++kk) {
            bf16x8 fa0 = Af[ra[0][kk]], fa1 = Af[ra[1][kk]];
            bf16x8 fb0 = Bf[rb[0][kk]], fb1 = Bf[rb[1][kk]];
            acc00 = __builtin_amdgcn_mfma_f32_16x16x32_bf16(fa0, fb0, acc00, 0, 0, 0);
            acc01 = __builtin_amdgcn_mfma_f32_16x16x32_bf16(fa0, fb1, acc01, 0, 0, 0);
            acc10 = __builtin_amdgcn_mfma_f32_16x16x32_bf16(fa1, fb0, acc10, 0, 0, 0);
            acc11 = __builtin_amdgcn_mfma_f32_16x16x32_bf16(fa1, fb1, acc11, 0, 0, 0);
        }
    }

    // stage gate tile to LDS (overlays staging buffers)
    __syncthreads();
    float* Ct = (float*)smem;   // [64][65]
    f32x4 av[2][2] = {{acc00, acc01}, {acc10, acc11}};
    #pragma unroll
    for (int i = 0; i < 2; ++i)
        #pragma unroll
        for (int j = 0; j < 2; ++j) {
            int mloc = wm * 32 + i * 16 + lg * 4;
            int nloc = wn * 32 + j * 16 + lr;
            #pragma unroll
            for (int r = 0; r < 4; ++r)
                Ct[(mloc + r) * 65 + nloc] = av[i][j][r];
        }
    __syncthreads();

    // LSTM pointwise: thread -> (m = tid>>4 strided, hloc = tid&15)
    int hloc = tid & 15;
    int h = (n0 >> 2) + hloc;
    #pragma unroll
    for (int q = 0; q < 4; ++q) {
        int m = (tid >> 4) + q * 16;
        int b = m0 + m;
        const float* crow = Ct + m * 65 + hloc * 4;
        const float* brow = bias + n0 + hloc * 4;
        float gi = crow[0] + brow[0];
        float gf = crow[1] + brow[1];
        float gg = crow[2] + brow[2];
        float go = crow[3] + brow[3];
        size_t idx = (size_t)b * NH + h;
        float c = sigm(gf) * cx[idx] + sigm(gi) * tanhf(gg);
        float hn = sigm(go) * tanhf(c);
        cx[idx] = c;
        hx[idx] = hn;
        hxAll[((size_t)t * NB + b) * NH + h] = (bf16_t)hn;
    }
}

// ------------------------------------------------------------------
// batched logits GEMM: A = hxAll [NS*NB, NH] bf16, B = fcWb [NV, NH],
// C row m -> out[(b*NS + t)*NV + n], b = m&127, t = m>>7. grid (38,157).
// ------------------------------------------------------------------
__global__ __launch_bounds__(256) void k_logits(
    const bf16_t* __restrict__ hxAll, const bf16_t* __restrict__ fcWb,
    const float* __restrict__ fc_b, float* __restrict__ out)
{
    __shared__ uint4 AsU[512];
    __shared__ uint4 BsU[512];
    int tid = threadIdx.x;
    int m0 = blockIdx.x * 64, n0 = blockIdx.y * 64;

    int rowS = tid >> 3, slotS = tid & 7;
    int wr0 = rowS * 8 + (slotS ^ (rowS & 7));
    int rowS2 = rowS + 32;
    int wr1 = rowS2 * 8 + (slotS ^ (rowS2 & 7));

    const uint4* pA = (const uint4*)(hxAll + (size_t)(m0 + rowS) * NH) + slotS;
    size_t aStep = (size_t)4 * NH;
    int nrow0 = n0 + rowS, nrow1 = n0 + rowS2;
    bool bv0 = nrow0 < NV, bv1 = nrow1 < NV;
    const uint4* pB0 = (const uint4*)(fcWb + (size_t)nrow0 * NH) + slotS;
    const uint4* pB1 = (const uint4*)(fcWb + (size_t)nrow1 * NH) + slotS;
    uint4 zz = make_uint4(0, 0, 0, 0);

    int w = tid >> 6, lane = tid & 63;
    int wm = w >> 1, wn = w & 1;
    int lr = lane & 15, lg = lane >> 4;
    int ra[2][2], rb[2][2];
    #pragma unroll
    for (int i = 0; i < 2; ++i)
        #pragma unroll
        for (int kk = 0; kk < 2; ++kk) {
            int rA = wm * 32 + i * 16 + lr;
            int rB = wn * 32 + i * 16 + lr;
            int s = kk * 4 + lg;
            ra[i][kk] = rA * 8 + (s ^ (rA & 7));
            rb[i][kk] = rB * 8 + (s ^ (rB & 7));
        }

    f32x4 acc00 = {}, acc01 = {}, acc10 = {}, acc11 = {};
    uint4 a0 = pA[0], a1 = pA[aStep];
    uint4 b0 = bv0 ? pB0[0] : zz;
    uint4 b1 = bv1 ? pB1[0] : zz;
    pA += 8; pB0 += 8; pB1 += 8;

    #pragma unroll 1
    for (int kt = 0; kt < NH / 64; ++kt) {
        __syncthreads();
        AsU[wr0] = a0; AsU[wr1] = a1;
        BsU[wr0] = b0; BsU[wr1] = b1;
        if (kt + 1 < NH / 64) {
            a0 = pA[0]; a1 = pA[aStep];
            b0 = bv0 ? pB0[0] : zz;
            b1 = bv1 ? pB1[0] : zz;
            pA += 8; pB0 += 8; pB1 += 8;
        }
        __syncthreads();
        const bf16x8* Af = (const bf16x8*)AsU;
        const bf16x8* Bf = (const bf16x8*)BsU;
        #pragma unroll
        for (int kk = 0; kk < 2; ++kk) {
            bf16x8 fa0 = Af[ra[0][kk]], fa1 = Af[ra[1][kk]];
            bf16x8 fb0 = Bf[rb[0][kk]], fb1 = Bf[rb[1][kk]];
            acc00 = __builtin_amdgcn_mfma_f32_16x16x32_bf16(fa0, fb0, acc00, 0, 0, 0);
            acc01 = __builtin_amdgcn_mfma_f32_16x16x32_bf16(fa0, fb1, acc01, 0, 0, 0);
            acc10 = __builtin_amdgcn_mfma_f32_16x16x32_bf16(fa1, fb0, acc10, 0, 0, 0);
            acc11 = __builtin_amdgcn_mfma_f32_16x16x32_bf16(fa1, fb1, acc11, 0, 0, 0);
        }
    }

    f32x4 av[2][2] = {{acc00, acc01}, {acc10, acc11}};
    #pragma unroll
    for (int i = 0; i < 2; ++i) {
        int mbase = m0 + wm * 32 + i * 16 + lg * 4;
        #pragma unroll
        for (int j = 0; j < 2; ++j) {
            int n = n0 + wn * 32 + j * 16 + lr;
            if (n < NV) {
                float bz = fc_b[n];
                #pragma unroll
                for (int r = 0; r < 4; ++r) {
                    int m = mbase + r;
                    int b = m & 127, tt = m >> 7;
                    out[((size_t)b * NS + tt) * NV + n] = av[i][j][r] + bz;
                }
            }
        }
    }
}

// ------------------------------------------------------------------
extern "C" void kernel_launch(void* const* d_in, const int* in_sizes, int n_in,
                              void* d_out, int out_size, void* d_ws, size_t ws_size,
                              hipStream_t stream)
{
    const float* features = (const float*)d_in[0];
    const int*   captions = (const int*)d_in[1];
    const float* emb      = (const float*)d_in[2];
    const float* W_h      = (const float*)d_in[3];
    const float* b_h      = (const float*)d_in[4];
    const float* W_f      = (const float*)d_in[5];
    const float* b_f      = (const float*)d_in[6];
    const float* v_w      = (const float*)d_in[7];
    // d_in[8] = v_b : cancels in softmax
    const float* W_ih     = (const float*)d_in[9];
    const float* W_hh     = (const float*)d_in[10];
    const float* b_ih     = (const float*)d_in[11];
    const float* b_hh     = (const float*)d_in[12];
    const float* fc_W     = (const float*)d_in[13];
    const float* fc_b     = (const float*)d_in[14];
    float* out = (float*)d_out;

    char* base = (char*)d_ws;
    bf16_t* Wcatb = (bf16_t*)base;  base += (size_t)NG * NKC * 2;        // 6,291,456
    bf16_t* fcWb  = (bf16_t*)base;  base += (size_t)NV * NH * 2;         // 10,240,000
    bf16_t* Wfb   = (bf16_t*)base;  base += (size_t)NA * NFD * 2;        // 262,144
    bf16_t* featb = (bf16_t*)base;  base += (size_t)NB * NR * NFD * 2;   // 6,422,528
    bf16_t* lin   = (bf16_t*)base;  base += (size_t)NB * NKC * 2;        // 393,216
    bf16_t* W_hb  = (bf16_t*)base;  base += (size_t)NA * NH * 2;         // 262,144
    bf16_t* hxAll = (bf16_t*)base;  base += (size_t)NS * NB * NH * 2;    // 2,490,368
    float* bias   = (float*)base;   base += (size_t)NG * 4;              // 8,192
    float* fproj  = (float*)base;   base += (size_t)NB * NR * NA * 4;    // 6,422,528
    float* hx     = (float*)base;   base += (size_t)NB * NH * 4;         // 262,144
    float* cx     = (float*)base;   base += (size_t)NB * NH * 4;         // 262,144
    // total ~33.3 MB

    k_setup<<<dim3((NV * NH + 255) / 256), 256, 0, stream>>>(
        W_ih, W_hh, b_ih, b_hh, W_h, fc_W, W_f, features,
        Wcatb, fcWb, Wfb, featb, W_hb, bias, hx, cx);

    // f_proj = features @ W_f^T + b_f : (6272 x 256), K=512
    gemm_bf16_nt<<<dim3(98, 4), 256, 0, stream>>>(
        featb, Wfb, b_f, fproj, NB * NR, NA, NFD, NA);

    for (int t = 0; t < NS; ++t) {
        k_attn<<<dim3(NB), 1024, 0, stream>>>(
            hx, W_hb, b_h, fproj, v_w, featb, emb, captions, lin, t);
        k_step<<<dim3(2, 32), 256, 0, stream>>>(
            lin, Wcatb, bias, hx, cx, hxAll, t);
    }

    // batched logits: (NS*NB x NV), K=512
    k_logits<<<dim3(38, 157), 256, 0, stream>>>(hxAll, fcWb, fc_b, out);
}